// Round 2
// 390.144 us; speedup vs baseline: 1.0479x; 1.0479x over previous
//
#include <hip/hip_runtime.h>
#include <hip/hip_bf16.h>
#include <math.h>
#include <stdint.h>

typedef __bf16 bf16x8 __attribute__((ext_vector_type(8)));
typedef __bf16 bf16x4 __attribute__((ext_vector_type(4)));
typedef float floatx4 __attribute__((ext_vector_type(4)));
typedef short shortx4 __attribute__((ext_vector_type(4)));
typedef unsigned int uint32x2 __attribute__((ext_vector_type(2)));

#define NQS   2048
#define NKVS  2048
#define NKV1  2049
#define DM    1024
#define NH    16
#define DHD   64
#define BATCH 2
#define ROWS  (BATCH * NQS)   // 4096

// async global->LDS, 16B per lane. LDS dest must be wave-uniform base + lane*16.
__device__ __forceinline__ void gld_lds16(const __bf16* gp, __bf16* lp) {
    __builtin_amdgcn_global_load_lds(
        (const __attribute__((address_space(1))) uint32_t*)(uintptr_t)gp,
        (__attribute__((address_space(3))) uint32_t*)(uintptr_t)lp,
        16, 0, 0);
}

// tanh-form GELU in exp2 domain: x * sigmoid(2*0.79788456*(x+0.044715x^3))
//  = x * rcp(1 + exp2(x*(c0 + c1*x^2))), c0=-2*log2e*0.79788456, c1=-2*log2e*0.03567741
__device__ __forceinline__ float gelu_fast(float x) {
    const float u = x * x;
    const float e = __builtin_amdgcn_exp2f(x * (-2.3022077f + (-0.1029431f) * u));
    return x * __builtin_amdgcn_rcpf(1.0f + e);
}

// ---------------------------------------------------------------------------
// Fused LayerNorm for X and Y (f32 in) -> bf16 out.  grid 2*ROWS.
// ---------------------------------------------------------------------------
__global__ __launch_bounds__(256) void ln2_to_bf16(
    const float* __restrict__ X, const float* __restrict__ Y,
    const float* __restrict__ g0, const float* __restrict__ b0,
    const float* __restrict__ g0kv, const float* __restrict__ b0kv,
    __bf16* __restrict__ Xn, __bf16* __restrict__ Yn)
{
    int row = blockIdx.x;
    const float *src, *gamma, *beta; __bf16* dst;
    if (row < ROWS) { src = X; gamma = g0; beta = b0; dst = Xn; }
    else { row -= ROWS; src = Y; gamma = g0kv; beta = b0kv; dst = Yn; }
    const int tid = threadIdx.x;
    const float4 v = ((const float4*)(src + (size_t)row * DM))[tid];
    float s  = v.x + v.y + v.z + v.w;
    float sq = v.x * v.x + v.y * v.y + v.z * v.z + v.w * v.w;
    for (int off = 1; off < 64; off <<= 1) {
        s  += __shfl_xor(s, off);
        sq += __shfl_xor(sq, off);
    }
    __shared__ float red[8];
    const int wave = tid >> 6, lane = tid & 63;
    if (lane == 0) { red[wave * 2] = s; red[wave * 2 + 1] = sq; }
    __syncthreads();
    s  = red[0] + red[2] + red[4] + red[6];
    sq = red[1] + red[3] + red[5] + red[7];
    const float mu  = s * (1.0f / DM);
    const float var = sq * (1.0f / DM) - mu * mu;
    const float rs  = rsqrtf(var + 1e-5f);
    const float4 gv = ((const float4*)gamma)[tid];
    const float4 bv = ((const float4*)beta)[tid];
    bf16x4 o;
    o[0] = (__bf16)((v.x - mu) * rs * gv.x + bv.x);
    o[1] = (__bf16)((v.y - mu) * rs * gv.y + bv.y);
    o[2] = (__bf16)((v.z - mu) * rs * gv.z + bv.z);
    o[3] = (__bf16)((v.w - mu) * rs * gv.w + bv.w);
    *(bf16x4*)(dst + (size_t)row * DM + tid * 4) = o;
}

// ---------------------------------------------------------------------------
// Residual add + LayerNorm: Hres = X + O (f32 out), Hr = LN(Hres) (bf16 out)
// ---------------------------------------------------------------------------
__global__ __launch_bounds__(256) void resid_ln(
    const float* __restrict__ X, const __bf16* __restrict__ O,
    const float* __restrict__ gamma, const float* __restrict__ beta,
    float* __restrict__ Hres, __bf16* __restrict__ Hr)
{
    const int row = blockIdx.x;
    const int tid = threadIdx.x;
    const float4 xv = ((const float4*)(X + (size_t)row * DM))[tid];
    const bf16x4 ov = *(const bf16x4*)(O + (size_t)row * DM + tid * 4);
    float4 v;
    v.x = xv.x + (float)ov[0];
    v.y = xv.y + (float)ov[1];
    v.z = xv.z + (float)ov[2];
    v.w = xv.w + (float)ov[3];
    ((float4*)(Hres + (size_t)row * DM))[tid] = v;

    float s  = v.x + v.y + v.z + v.w;
    float sq = v.x * v.x + v.y * v.y + v.z * v.z + v.w * v.w;
    for (int off = 1; off < 64; off <<= 1) {
        s  += __shfl_xor(s, off);
        sq += __shfl_xor(sq, off);
    }
    __shared__ float red[8];
    const int wave = tid >> 6, lane = tid & 63;
    if (lane == 0) { red[wave * 2] = s; red[wave * 2 + 1] = sq; }
    __syncthreads();
    s  = red[0] + red[2] + red[4] + red[6];
    sq = red[1] + red[3] + red[5] + red[7];
    const float mu  = s * (1.0f / DM);
    const float var = sq * (1.0f / DM) - mu * mu;
    const float rs  = rsqrtf(var + 1e-5f);
    const float4 gv = ((const float4*)gamma)[tid];
    const float4 bv = ((const float4*)beta)[tid];
    bf16x4 o;
    o[0] = (__bf16)((v.x - mu) * rs * gv.x + bv.x);
    o[1] = (__bf16)((v.y - mu) * rs * gv.y + bv.y);
    o[2] = (__bf16)((v.z - mu) * rs * gv.z + bv.z);
    o[3] = (__bf16)((v.w - mu) * rs * gv.w + bv.w);
    *(bf16x4*)(Hr + (size_t)row * DM + tid * 4) = o;
}

// Fused transpose of the three 1024x1024 QKV weights (one launch, z picks W).
__global__ __launch_bounds__(256) void transpose3_f32_bf16(
    const float* __restrict__ Wq, const float* __restrict__ Wk,
    const float* __restrict__ Wv, __bf16* __restrict__ WqT,
    __bf16* __restrict__ WkT, __bf16* __restrict__ WvT)
{
    __shared__ float tile[32][33];
    const int z = blockIdx.z;
    const float* in = (z == 0) ? Wq : (z == 1) ? Wk : Wv;
    __bf16* out = (z == 0) ? WqT : (z == 1) ? WkT : WvT;
    const int c0 = blockIdx.x * 32, r0 = blockIdx.y * 32;
    const int tx = threadIdx.x, ty = threadIdx.y;
#pragma unroll
    for (int i = 0; i < 4; i++)
        tile[ty + i * 8][tx] = in[(size_t)(r0 + ty + i * 8) * DM + c0 + tx];
    __syncthreads();
#pragma unroll
    for (int i = 0; i < 4; i++)
        out[(size_t)(c0 + ty + i * 8) * DM + r0 + tx] = (__bf16)tile[tx][ty + i * 8];
}

// Fused transpose of W1 [1024][4096] and W2 [4096][1024] (z picks).
__global__ __launch_bounds__(256) void transpose_ffw(
    const float* __restrict__ W1, const float* __restrict__ W2,
    __bf16* __restrict__ W1T, __bf16* __restrict__ W2T)
{
    __shared__ float tile[32][33];
    const int z = blockIdx.z;
    const float* in; __bf16* out; int R, C, c0, r0;
    if (z == 0) { in = W1; out = W1T; R = DM; C = 4 * DM; c0 = blockIdx.x * 32; r0 = blockIdx.y * 32; }
    else        { in = W2; out = W2T; R = 4 * DM; C = DM; c0 = blockIdx.y * 32; r0 = blockIdx.x * 32; }
    const int tx = threadIdx.x, ty = threadIdx.y;
#pragma unroll
    for (int i = 0; i < 4; i++)
        tile[ty + i * 8][tx] = in[(size_t)(r0 + ty + i * 8) * C + c0 + tx];
    __syncthreads();
#pragma unroll
    for (int i = 0; i < 4; i++)
        out[(size_t)(c0 + ty + i * 8) * R + r0 + tx] = (__bf16)tile[tx][ty + i * 8];
}

// ---------------------------------------------------------------------------
// Fill null-K row (kv==2048) with null_k, and zero Vt pad columns [2048,2056)
// ---------------------------------------------------------------------------
__global__ __launch_bounds__(256) void fill_null(
    const float* __restrict__ null_k, __bf16* __restrict__ Kb,
    __bf16* __restrict__ Vt)
{
    const int i = blockIdx.x * 256 + threadIdx.x;
    if (i < BATCH * DM) {
        const int b = i >> 10, d = i & (DM - 1);
        Kb[((size_t)b * NKV1 + NKVS) * DM + d] = (__bf16)null_k[d];
    }
    if (i < BATCH * NH * DHD * 8) {  // 16384
        const int bhd = i >> 3, kvp = i & 7;
        Vt[(size_t)bhd * 2056 + 2048 + kvp] = (__bf16)0.0f;
    }
}

// ---------------------------------------------------------------------------
// GEMM  C = A @ Bt^T + bias   (A: [M][K] bf16, Bt: [N][K] bf16)
// 128x128 tile, BK=32, 256 threads (4 waves, 64x64 each), mfma 16x16x32 bf16.
// MODE 0: bf16 flat [M][N]
// MODE 4: split-K partials -- blockIdx.z = K-slice (K/4); raw f32 partial.
// ACT 1: fast tanh-form GELU (exp2+rcp; exact-erf erff was 48% VALUBusy)
// ---------------------------------------------------------------------------
template<int MODE, int ACT>
__global__ __launch_bounds__(256) void gemm_bt(
    const __bf16* __restrict__ A, const __bf16* __restrict__ Bt,
    const float* __restrict__ bias, void* __restrict__ outp,
    const float* __restrict__ resid, int M, int N, int K)
{
    __shared__ __bf16 As[128][32];
    __shared__ __bf16 Bs[128][32];
    const int tid  = threadIdx.x;
    const int lane = tid & 63, wave = tid >> 6;
    const int g = lane >> 4, c = lane & 15;
    const int m0 = blockIdx.y * 128, n0 = blockIdx.x * 128;
    const int wm = (wave >> 1) * 64, wn = (wave & 1) * 64;

    floatx4 acc[4][4] = {};

    const int srow = tid >> 2;
    const int schk = (tid & 3) * 8;
    const __bf16* Ag = A  + (size_t)(m0 + srow) * K + schk;
    const __bf16* Bg = Bt + (size_t)(n0 + srow) * K + schk;
    __bf16* lA0 = &As[srow][schk];
    __bf16* lA1 = &As[srow + 64][schk];
    __bf16* lB0 = &Bs[srow][schk];
    __bf16* lB1 = &Bs[srow + 64][schk];

    int kbeg = 0, kend = K;
    if (MODE == 4) { const int KS = K >> 2; kbeg = blockIdx.z * KS; kend = kbeg + KS; }

    for (int k0 = kbeg; k0 < kend; k0 += 32) {
        __syncthreads();
        gld_lds16(Ag + k0, lA0);
        gld_lds16(Ag + (size_t)64 * K + k0, lA1);
        gld_lds16(Bg + k0, lB0);
        gld_lds16(Bg + (size_t)64 * K + k0, lB1);
        __syncthreads();
        bf16x8 af[4], bfr[4];
#pragma unroll
        for (int i = 0; i < 4; i++) af[i]  = *(const bf16x8*)&As[wm + i * 16 + c][g * 8];
#pragma unroll
        for (int j = 0; j < 4; j++) bfr[j] = *(const bf16x8*)&Bs[wn + j * 16 + c][g * 8];
#pragma unroll
        for (int i = 0; i < 4; i++)
#pragma unroll
            for (int j = 0; j < 4; j++)
                acc[i][j] = __builtin_amdgcn_mfma_f32_16x16x32_bf16(af[i], bfr[j], acc[i][j], 0, 0, 0);
    }

    __bf16* obf = (__bf16*)outp;
    float*  of  = (float*)outp;
#pragma unroll
    for (int i = 0; i < 4; i++) {
#pragma unroll
        for (int j = 0; j < 4; j++) {
            const int row = m0 + wm + i * 16 + g * 4;
            const int col = n0 + wn + j * 16 + c;
            const float bb = (MODE == 4) ? 0.0f : bias[col];
            float xs[4];
#pragma unroll
            for (int r = 0; r < 4; r++) {
                float x = acc[i][j][r] + bb;
                if (ACT == 1) x = gelu_fast(x);
                xs[r] = x;
            }
            if (MODE == 0) {
#pragma unroll
                for (int r = 0; r < 4; r++)
                    obf[(size_t)(row + r) * N + col] = (__bf16)xs[r];
            } else if (MODE == 4) {
#pragma unroll
                for (int r = 0; r < 4; r++)
                    of[((size_t)blockIdx.z * M + row + r) * N + col] = xs[r];
            }
        }
    }
}

// ---------------------------------------------------------------------------
// Fused Q/K/V projection GEMM.  grid (8, 32, 3) = 768 blocks = 3 blocks/CU.
// ---------------------------------------------------------------------------
__global__ __launch_bounds__(256) void qkv_gemm(
    const __bf16* __restrict__ Xn, const __bf16* __restrict__ Yn,
    const __bf16* __restrict__ WqT, const __bf16* __restrict__ WkT,
    const __bf16* __restrict__ WvT,
    const float* __restrict__ bq, const float* __restrict__ bk,
    const float* __restrict__ bv,
    __bf16* __restrict__ Qbf, __bf16* __restrict__ Kbf,
    __bf16* __restrict__ Vt)
{
    __shared__ __bf16 As[128][32];
    __shared__ __bf16 Bs[128][32];
    const int z = blockIdx.z;
    const __bf16* A    = (z == 0) ? Xn  : Yn;
    const __bf16* Bt   = (z == 0) ? WqT : (z == 1) ? WkT : WvT;
    const float*  bias = (z == 0) ? bq  : (z == 1) ? bk  : bv;

    const int tid  = threadIdx.x;
    const int lane = tid & 63, wave = tid >> 6;
    const int g = lane >> 4, c = lane & 15;
    const int m0 = blockIdx.y * 128, n0 = blockIdx.x * 128;
    const int wm = (wave >> 1) * 64, wn = (wave & 1) * 64;

    floatx4 acc[4][4] = {};

    const int srow = tid >> 2;
    const int schk = (tid & 3) * 8;
    const __bf16* Ag = A  + (size_t)(m0 + srow) * DM + schk;
    const __bf16* Bg = Bt + (size_t)(n0 + srow) * DM + schk;
    __bf16* lA0 = &As[srow][schk];
    __bf16* lA1 = &As[srow + 64][schk];
    __bf16* lB0 = &Bs[srow][schk];
    __bf16* lB1 = &Bs[srow + 64][schk];

    for (int k0 = 0; k0 < DM; k0 += 32) {
        __syncthreads();
        gld_lds16(Ag + k0, lA0);
        gld_lds16(Ag + (size_t)64 * DM + k0, lA1);
        gld_lds16(Bg + k0, lB0);
        gld_lds16(Bg + (size_t)64 * DM + k0, lB1);
        __syncthreads();
        bf16x8 af[4], bfr[4];
#pragma unroll
        for (int i = 0; i < 4; i++) af[i]  = *(const bf16x8*)&As[wm + i * 16 + c][g * 8];
#pragma unroll
        for (int j = 0; j < 4; j++) bfr[j] = *(const bf16x8*)&Bs[wn + j * 16 + c][g * 8];
#pragma unroll
        for (int i = 0; i < 4; i++)
#pragma unroll
            for (int j = 0; j < 4; j++)
                acc[i][j] = __builtin_amdgcn_mfma_f32_16x16x32_bf16(af[i], bfr[j], acc[i][j], 0, 0, 0);
    }

#pragma unroll
    for (int i = 0; i < 4; i++) {
#pragma unroll
        for (int j = 0; j < 4; j++) {
            const int row = m0 + wm + i * 16 + g * 4;
            const int col = n0 + wn + j * 16 + c;
            const float bb = bias[col];
            float xs[4];
#pragma unroll
            for (int r = 0; r < 4; r++) xs[r] = acc[i][j][r] + bb;
            if (z == 0) {
#pragma unroll
                for (int r = 0; r < 4; r++)
                    Qbf[(size_t)(row + r) * DM + col] = (__bf16)xs[r];
            } else if (z == 1) {
#pragma unroll
                for (int r = 0; r < 4; r++) {
                    const int rr = row + r;
                    Kbf[(size_t)(rr + (rr >> 11)) * DM + col] = (__bf16)xs[r];
                }
            } else {
                const int b  = row >> 11;
                const int kv = row & 2047;
                const size_t base =
                    ((size_t)((b * NH + (col >> 6)) * DHD + (col & 63))) * 2056 + kv;
                bf16x4 pk;
                pk[0] = (__bf16)xs[0]; pk[1] = (__bf16)xs[1];
                pk[2] = (__bf16)xs[2]; pk[3] = (__bf16)xs[3];
                *(bf16x4*)(Vt + base) = pk;
            }
        }
    }
}

// ---------------------------------------------------------------------------
// FF2 split-K reduction: out = sum_z partials[z] + bias + Hres.  float4/thread.
// ---------------------------------------------------------------------------
__global__ __launch_bounds__(256) void ff2_reduce(
    const float* __restrict__ part, const float* __restrict__ bias,
    const float* __restrict__ Hres, float* __restrict__ out)
{
    const size_t f4 = (size_t)blockIdx.x * 256 + threadIdx.x;  // float4 index
    const int c4 = (int)(f4 & (DM / 4 - 1));
    const size_t stride4 = (size_t)ROWS * DM / 4;
    float4 a = ((const float4*)part)[f4];
    const float4 p1 = ((const float4*)part)[f4 + stride4];
    const float4 p2 = ((const float4*)part)[f4 + 2 * stride4];
    const float4 p3 = ((const float4*)part)[f4 + 3 * stride4];
    const float4 b  = ((const float4*)bias)[c4];
    const float4 hr = ((const float4*)Hres)[f4];
    a.x += p1.x + p2.x + p3.x + b.x + hr.x;
    a.y += p1.y + p2.y + p3.y + b.y + hr.y;
    a.z += p1.z + p2.z + p3.z + b.z + hr.z;
    a.w += p1.w + p2.w + p3.w + b.w + hr.w;
    ((float4*)out)[f4] = a;
}

// ---------------------------------------------------------------------------
// Flash attention v2: S^T formulation, fixed-shift softmax.
//  - 128 q-rows/block, 4 waves, 32 q-rows/wave (2 q-subtiles): halves the
//    per-work LDS read traffic vs 16 q/wave (K/V tile read 4x -> 2x redundant).
//  - K/V staged via global_load_lds (linear dest) with XOR-swizzled SOURCE:
//    physical 16B slot s of row r holds logical chunk s^(r&7); reads apply
//    the same involution. (Unpadded [64][64] would be 16-way conflicted.)
//  - flat grid 512, XCD-aware decode: blockIdx%8 picks (b,h) group so all 16
//    q-tiles of one (b,h) share one XCD's L2 (K/V ~1MB per head).
//  - one barrier per KV tile (stage next -> compute cur -> barrier).
// ---------------------------------------------------------------------------
__global__ __launch_bounds__(256, 2) void attn_kernel(
    const __bf16* __restrict__ Q, const __bf16* __restrict__ Kb,
    const __bf16* __restrict__ Vt, __bf16* __restrict__ O)
{
    __shared__ __bf16 Ks[2][64][64];   // [kv][d]   16 KB
    __shared__ __bf16 Vs[2][64][64];   // [d][kv]   16 KB

    const int tid = threadIdx.x, lane = tid & 63, w = tid >> 6;
    const int g = lane >> 4, c = lane & 15;

    // XCD-aware decode: hw%8 = XCD slice; each XCD owns hb in {x, x+8, x+16, x+24}
    const int hw   = blockIdx.x;
    const int slot = hw >> 3;
    const int hb   = (hw & 7) | ((slot >> 4) << 3);   // 0..31
    const int h = hb & 15, b = hb >> 4;
    const int q0w = (slot & 15) * 128 + w * 32;

    // Q fragments prescaled by log2(e)/32: softmax runs in exp2 domain.
    const float QSC = 0.03125f * 1.44269504088896f;
    bf16x8 qf[2][2];
#pragma unroll
    for (int qt = 0; qt < 2; qt++) {
        const __bf16* Qbase = Q + ((size_t)(b * NQS + q0w + qt * 16 + c)) * DM + h * DHD;
        qf[qt][0] = *(const bf16x8*)(Qbase + g * 8);
        qf[qt][1] = *(const bf16x8*)(Qbase + 32 + g * 8);
#pragma unroll
        for (int e = 0; e < 8; e++) {
            qf[qt][0][e] = (__bf16)((float)qf[qt][0][e] * QSC);
            qf[qt][1][e] = (__bf16)((float)qf[qt][1][e] * QSC);
        }
    }

    floatx4 lacc[2] = {};        // per-lane partial softmax denominator (per qt)
    floatx4 oacc[2][4] = {};

    // staging: thread tid fills LDS bytes [tid*16, tid*16+16) of each 32-row
    // half (linear dest for global_load_lds); source chunk pre-swizzled.
    const int srow = tid >> 3;                    // LDS row 0..31 (and +32)
    const int schk = (tid & 7) ^ (srow & 7);      // swizzled 16B source chunk
    const __bf16* Kg  = Kb + (size_t)b * NKV1 * DM + h * DHD + schk * 8;
    const __bf16* Vg  = Vt + ((size_t)(b * NH + h) * DHD + srow) * 2056;
    const __bf16* Vg2 = Vg + (size_t)32 * 2056;
    const int vcol0 = schk * 8;

    auto stage = [&](int p, int kv0, bool tail) {
        __bf16* kd0 = &Ks[p][0][0]  + tid * 8;
        __bf16* kd1 = &Ks[p][32][0] + tid * 8;
        __bf16* vd0 = &Vs[p][0][0]  + tid * 8;
        __bf16* vd1 = &Vs[p][32][0] + tid * 8;
        if (!tail) {
            gld_lds16(Kg + (size_t)(kv0 + srow) * DM, kd0);
            gld_lds16(Kg + (size_t)(kv0 + srow + 32) * DM, kd1);
            gld_lds16(Vg + kv0 + vcol0, vd0);
            gld_lds16(Vg2 + kv0 + vcol0, vd1);
        } else {
            // clamp: K rows >2048 re-read null row (masked later); V cols
            // clamp to 2048 -> reads zero pad (p=0 masks kv>2048; V[2048]=0).
            const int r0 = min(kv0 + srow, NKVS);
            const int r1 = min(kv0 + srow + 32, NKVS);
            const int vc = min(kv0 + vcol0, NKVS);
            gld_lds16(Kg + (size_t)r0 * DM, kd0);
            gld_lds16(Kg + (size_t)r1 * DM, kd1);
            gld_lds16(Vg + vc, vd0);
            gld_lds16(Vg2 + vc, vd1);
        }
    };

    auto compute = [&](int p, int kv0, bool tail) {
        // S^T = K Q^T - 6  (accumulator pre-init folds the softmax shift)
        floatx4 s[2][4];
#pragma unroll
        for (int qt = 0; qt < 2; qt++)
#pragma unroll
            for (int kvt = 0; kvt < 4; kvt++)
#pragma unroll
                for (int r = 0; r < 4; r++) s[qt][kvt][r] = -6.0f;

        const int sw = c & 7;   // row&7 for all our read rows (row = kvt*16+c)
        __builtin_amdgcn_s_setprio(1);
#pragma unroll
        for (int kvt = 0; kvt < 4; kvt++) {
            const bf16x8 kf0 = *(const bf16x8*)&Ks[p][kvt * 16 + c][(g ^ sw) * 8];
            const bf16x8 kf1 = *(const bf16x8*)&Ks[p][kvt * 16 + c][((4 | g) ^ sw) * 8];
#pragma unroll
            for (int qt = 0; qt < 2; qt++) {
                s[qt][kvt] = __builtin_amdgcn_mfma_f32_16x16x32_bf16(kf0, qf[qt][0], s[qt][kvt], 0, 0, 0);
                s[qt][kvt] = __builtin_amdgcn_mfma_f32_16x16x32_bf16(kf1, qf[qt][1], s[qt][kvt], 0, 0, 0);
            }
        }
        __builtin_amdgcn_s_setprio(0);

        if (tail) {
#pragma unroll
            for (int qt = 0; qt < 2; qt++)
#pragma unroll
                for (int kvt = 0; kvt < 4; kvt++)
#pragma unroll
                    for (int r = 0; r < 4; r++)
                        if (kv0 + kvt * 16 + g * 4 + r >= NKV1) s[qt][kvt][r] = -1e30f;
        }

        // p = exp2(s); accumulate denominator; pack to bf16 by truncation
        shortx4 pf[2][4];
#pragma unroll
        for (int qt = 0; qt < 2; qt++)
#pragma unroll
            for (int kvt = 0; kvt < 4; kvt++) {
                float p0 = __builtin_amdgcn_exp2f(s[qt][kvt][0]);
                float p1 = __builtin_amdgcn_exp2f(s[qt][kvt][1]);
                float p2 = __builtin_amdgcn_exp2f(s[qt][kvt][2]);
                float p3 = __builtin_amdgcn_exp2f(s[qt][kvt][3]);
                lacc[qt][0] += p0; lacc[qt][1] += p1;
                lacc[qt][2] += p2; lacc[qt][3] += p3;
                uint32x2 pk;
                pk[0] = (__builtin_bit_cast(unsigned int, p0) >> 16) |
                        (__builtin_bit_cast(unsigned int, p1) & 0xFFFF0000u);
                pk[1] = (__builtin_bit_cast(unsigned int, p2) >> 16) |
                        (__builtin_bit_cast(unsigned int, p3) & 0xFFFF0000u);
                pf[qt][kvt] = __builtin_bit_cast(shortx4, pk);
            }

        // O^T += V^T P^T
        __builtin_amdgcn_s_setprio(1);
#pragma unroll
        for (int kvt = 0; kvt < 4; kvt++) {
            shortx4 vfr[4];
#pragma unroll
            for (int dt = 0; dt < 4; dt++) {
                // logical col bytes = kvt*32 + g*8 -> slot kvt*2+(g>>1), off (g&1)*8
                const int slotp = (kvt * 2 + (g >> 1)) ^ sw;
                vfr[dt] = *(const shortx4*)&Vs[p][dt * 16 + c][slotp * 8 + (g & 1) * 4];
            }
#pragma unroll
            for (int dt = 0; dt < 4; dt++)
#pragma unroll
                for (int qt = 0; qt < 2; qt++)
                    oacc[qt][dt] = __builtin_amdgcn_mfma_f32_16x16x16bf16_1k(
                        vfr[dt], pf[qt][kvt], oacc[qt][dt], 0, 0, 0);
        }
        __builtin_amdgcn_s_setprio(0);
    };

    // prologue: tile 0 -> buf 0
    stage(0, 0, false);
    __syncthreads();
    for (int it = 0; it < 32; it++) {
        stage((it + 1) & 1, (it + 1) * 64, it == 31);  // prefetch next tile
        compute(it & 1, it * 64, false);               // tiles 0..31 all full
        __syncthreads();                               // vmcnt(0)+barrier
    }
    compute(0, 2048, true);                            // tail tile in buf 0

    // denominator: per-lane partials -> per-q total (2 shuffles per qt)
#pragma unroll
    for (int qt = 0; qt < 2; qt++) {
        float l = lacc[qt][0] + lacc[qt][1] + lacc[qt][2] + lacc[qt][3];
        l += __shfl_xor(l, 16);
        l += __shfl_xor(l, 32);
        const float inv_l = 1.0f / l;
        __bf16* Ob = O + ((size_t)(b * NQS + q0w + qt * 16 + c)) * DM + h * DHD;
#pragma unroll
        for (int dt = 0; dt < 4; dt++) {
            bf16x4 ob;
#pragma unroll
            for (int r = 0; r < 4; r++) ob[r] = (__bf16)(oacc[qt][dt][r] * inv_l);
            *(bf16x4*)(Ob + dt * 16 + g * 4) = ob;
        }
    }
}

// ---------------------------------------------------------------------------
extern "C" void kernel_launch(void* const* d_in, const int* in_sizes, int n_in,
                              void* d_out, int out_size, void* d_ws, size_t ws_size,
                              hipStream_t stream)
{
    const float* X      = (const float*)d_in[0];
    const float* Y      = (const float*)d_in[1];
    const float* Wq     = (const float*)d_in[2];
    const float* bq     = (const float*)d_in[3];
    const float* Wk     = (const float*)d_in[4];
    const float* bk     = (const float*)d_in[5];
    const float* Wv     = (const float*)d_in[6];
    const float* bv     = (const float*)d_in[7];
    const float* null_k = (const float*)d_in[8];
    const float* g0     = (const float*)d_in[9];
    const float* b0     = (const float*)d_in[10];
    const float* g0kv   = (const float*)d_in[11];
    const float* b0kv   = (const float*)d_in[12];
    const float* g1     = (const float*)d_in[13];
    const float* b1     = (const float*)d_in[14];
    const float* W1     = (const float*)d_in[15];
    const float* bf1    = (const float*)d_in[16];
    const float* W2     = (const float*)d_in[17];
    const float* bf2    = (const float*)d_in[18];
    float* out = (float*)d_out;

    // workspace carve (bytes).  Persistent-through-FF2 buffers FIRST so the
    // tail region (dead by FF2 time) can be reused for split-K partials.
    char* p = (char*)d_ws;
    __bf16* W2T  = (__bf16*)p; p += (size_t)4 * DM * DM * 2;          // [1024][4096]
    float*  Hres = (float*)p;  p += (size_t)ROWS * DM * 4;
    __bf16* Gbf  = (__bf16*)p; p += (size_t)ROWS * 4 * DM * 2;
    char* scratch = p;                                                // dead by FF2
    __bf16* Xn   = (__bf16*)p; p += (size_t)ROWS * DM * 2;
    __bf16* Yn   = (__bf16*)p; p += (size_t)ROWS * DM * 2;
    __bf16* WqT  = (__bf16*)p; p += (size_t)DM * DM * 2;
    __bf16* WkT  = (__bf16*)p; p += (size_t)DM * DM * 2;
    __bf16* WvT  = (__bf16*)p; p += (size_t)DM * DM * 2;
    __bf16* W1T  = (__bf16*)p; p += (size_t)4 * DM * DM * 2;          // [4096][1024]
    __bf16* Qbf  = (__bf16*)p; p += (size_t)ROWS * DM * 2;
    __bf16* Kbf  = (__bf16*)p; p += (size_t)BATCH * NKV1 * DM * 2;
    __bf16* Vt   = (__bf16*)p; p += (size_t)BATCH * NH * DHD * 2056 * 2;
    __bf16* Obf  = (__bf16*)p; p += (size_t)ROWS * DM * 2;
    __bf16* Hr   = (__bf16*)p; p += (size_t)ROWS * DM * 2;
    float* Part  = (float*)scratch;  // FF2 partials: 4 x ROWS x DM f32 = 67 MB

    // 1. LayerNorms (fused X+Y, one launch)
    ln2_to_bf16<<<2 * ROWS, 256, 0, stream>>>(X, Y, g0, b0, g0kv, b0kv, Xn, Yn);

    // 2. weight transposes (f32 -> bf16, W^T), two launches total
    transpose3_f32_bf16<<<dim3(DM / 32, DM / 32, 3), dim3(32, 8), 0, stream>>>(
        Wq, Wk, Wv, WqT, WkT, WvT);
    transpose_ffw<<<dim3(128, 32, 2), dim3(32, 8), 0, stream>>>(W1, W2, W1T, W2T);

    // 3. fused Q/K/V projections (768 blocks = 3 blocks/CU)
    qkv_gemm<<<dim3(DM / 128, ROWS / 128, 3), 256, 0, stream>>>(
        Xn, Yn, WqT, WkT, WvT, bq, bk, bv, Qbf, Kbf, Vt);
    fill_null<<<64, 256, 0, stream>>>(null_k, Kbf, Vt);

    // 4. attention (128 q/block, gld_lds staging, XCD-local heads)
    attn_kernel<<<dim3(512), 256, 0, stream>>>(Qbf, Kbf, Vt, Obf);

    // 5. residual + LN
    resid_ln<<<ROWS, 256, 0, stream>>>(X, Obf, g1, b1, Hres, Hr);

    // 6. FFN
    gemm_bt<0, 1><<<dim3(4 * DM / 128, ROWS / 128), 256, 0, stream>>>(
        Hr, W1T, bf1, (void*)Gbf, nullptr, ROWS, 4 * DM, DM);
    // FF2 split-K=4 (1024 blocks = 4 blocks/CU), then reduce + bias + resid
    gemm_bt<4, 0><<<dim3(DM / 128, ROWS / 128, 4), 256, 0, stream>>>(
        Gbf, W2T, bf2, (void*)Part, nullptr, ROWS, DM, 4 * DM);
    ff2_reduce<<<ROWS * DM / 1024, 256, 0, stream>>>(Part, bf2, Hres, out);
}

// Round 3
// 349.090 us; speedup vs baseline: 1.1711x; 1.1176x over previous
//
#include <hip/hip_runtime.h>
#include <hip/hip_bf16.h>
#include <math.h>
#include <stdint.h>

typedef __bf16 bf16x8 __attribute__((ext_vector_type(8)));
typedef __bf16 bf16x4 __attribute__((ext_vector_type(4)));
typedef float floatx4 __attribute__((ext_vector_type(4)));
typedef short shortx4 __attribute__((ext_vector_type(4)));
typedef unsigned int uint32x2 __attribute__((ext_vector_type(2)));

#define NQS   2048
#define NKVS  2048
#define NKV1  2049
#define DM    1024
#define NH    16
#define DHD   64
#define BATCH 2
#define ROWS  (BATCH * NQS)   // 4096

// async global->LDS, 16B per lane. LDS dest must be wave-uniform base + lane*16.
__device__ __forceinline__ void gld_lds16(const __bf16* gp, __bf16* lp) {
    __builtin_amdgcn_global_load_lds(
        (const __attribute__((address_space(1))) uint32_t*)(uintptr_t)gp,
        (__attribute__((address_space(3))) uint32_t*)(uintptr_t)lp,
        16, 0, 0);
}

// tanh-form GELU in exp2 domain
__device__ __forceinline__ float gelu_fast(float x) {
    const float u = x * x;
    const float e = __builtin_amdgcn_exp2f(x * (-2.3022077f + (-0.1029431f) * u));
    return x * __builtin_amdgcn_rcpf(1.0f + e);
}

// ---------------------------------------------------------------------------
// Fused LayerNorm for X and Y (f32 in) -> bf16 out.  grid 2*ROWS.
// ---------------------------------------------------------------------------
__global__ __launch_bounds__(256) void ln2_to_bf16(
    const float* __restrict__ X, const float* __restrict__ Y,
    const float* __restrict__ g0, const float* __restrict__ b0,
    const float* __restrict__ g0kv, const float* __restrict__ b0kv,
    __bf16* __restrict__ Xn, __bf16* __restrict__ Yn)
{
    int row = blockIdx.x;
    const float *src, *gamma, *beta; __bf16* dst;
    if (row < ROWS) { src = X; gamma = g0; beta = b0; dst = Xn; }
    else { row -= ROWS; src = Y; gamma = g0kv; beta = b0kv; dst = Yn; }
    const int tid = threadIdx.x;
    const float4 v = ((const float4*)(src + (size_t)row * DM))[tid];
    float s  = v.x + v.y + v.z + v.w;
    float sq = v.x * v.x + v.y * v.y + v.z * v.z + v.w * v.w;
    for (int off = 1; off < 64; off <<= 1) {
        s  += __shfl_xor(s, off);
        sq += __shfl_xor(sq, off);
    }
    __shared__ float red[8];
    const int wave = tid >> 6, lane = tid & 63;
    if (lane == 0) { red[wave * 2] = s; red[wave * 2 + 1] = sq; }
    __syncthreads();
    s  = red[0] + red[2] + red[4] + red[6];
    sq = red[1] + red[3] + red[5] + red[7];
    const float mu  = s * (1.0f / DM);
    const float var = sq * (1.0f / DM) - mu * mu;
    const float rs  = rsqrtf(var + 1e-5f);
    const float4 gv = ((const float4*)gamma)[tid];
    const float4 bv = ((const float4*)beta)[tid];
    bf16x4 o;
    o[0] = (__bf16)((v.x - mu) * rs * gv.x + bv.x);
    o[1] = (__bf16)((v.y - mu) * rs * gv.y + bv.y);
    o[2] = (__bf16)((v.z - mu) * rs * gv.z + bv.z);
    o[3] = (__bf16)((v.w - mu) * rs * gv.w + bv.w);
    *(bf16x4*)(dst + (size_t)row * DM + tid * 4) = o;
}

// ---------------------------------------------------------------------------
// Residual add + LayerNorm: Hres = X + O (f32 out), Hr = LN(Hres) (bf16 out)
// ---------------------------------------------------------------------------
__global__ __launch_bounds__(256) void resid_ln(
    const float* __restrict__ X, const __bf16* __restrict__ O,
    const float* __restrict__ gamma, const float* __restrict__ beta,
    float* __restrict__ Hres, __bf16* __restrict__ Hr)
{
    const int row = blockIdx.x;
    const int tid = threadIdx.x;
    const float4 xv = ((const float4*)(X + (size_t)row * DM))[tid];
    const bf16x4 ov = *(const bf16x4*)(O + (size_t)row * DM + tid * 4);
    float4 v;
    v.x = xv.x + (float)ov[0];
    v.y = xv.y + (float)ov[1];
    v.z = xv.z + (float)ov[2];
    v.w = xv.w + (float)ov[3];
    ((float4*)(Hres + (size_t)row * DM))[tid] = v;

    float s  = v.x + v.y + v.z + v.w;
    float sq = v.x * v.x + v.y * v.y + v.z * v.z + v.w * v.w;
    for (int off = 1; off < 64; off <<= 1) {
        s  += __shfl_xor(s, off);
        sq += __shfl_xor(sq, off);
    }
    __shared__ float red[8];
    const int wave = tid >> 6, lane = tid & 63;
    if (lane == 0) { red[wave * 2] = s; red[wave * 2 + 1] = sq; }
    __syncthreads();
    s  = red[0] + red[2] + red[4] + red[6];
    sq = red[1] + red[3] + red[5] + red[7];
    const float mu  = s * (1.0f / DM);
    const float var = sq * (1.0f / DM) - mu * mu;
    const float rs  = rsqrtf(var + 1e-5f);
    const float4 gv = ((const float4*)gamma)[tid];
    const float4 bv = ((const float4*)beta)[tid];
    bf16x4 o;
    o[0] = (__bf16)((v.x - mu) * rs * gv.x + bv.x);
    o[1] = (__bf16)((v.y - mu) * rs * gv.y + bv.y);
    o[2] = (__bf16)((v.z - mu) * rs * gv.z + bv.z);
    o[3] = (__bf16)((v.w - mu) * rs * gv.w + bv.w);
    *(bf16x4*)(Hr + (size_t)row * DM + tid * 4) = o;
}

// Fused transpose of the three 1024x1024 QKV weights (one launch, z picks W).
__global__ __launch_bounds__(256) void transpose3_f32_bf16(
    const float* __restrict__ Wq, const float* __restrict__ Wk,
    const float* __restrict__ Wv, __bf16* __restrict__ WqT,
    __bf16* __restrict__ WkT, __bf16* __restrict__ WvT)
{
    __shared__ float tile[32][33];
    const int z = blockIdx.z;
    const float* in = (z == 0) ? Wq : (z == 1) ? Wk : Wv;
    __bf16* out = (z == 0) ? WqT : (z == 1) ? WkT : WvT;
    const int c0 = blockIdx.x * 32, r0 = blockIdx.y * 32;
    const int tx = threadIdx.x, ty = threadIdx.y;
#pragma unroll
    for (int i = 0; i < 4; i++)
        tile[ty + i * 8][tx] = in[(size_t)(r0 + ty + i * 8) * DM + c0 + tx];
    __syncthreads();
#pragma unroll
    for (int i = 0; i < 4; i++)
        out[(size_t)(c0 + ty + i * 8) * DM + r0 + tx] = (__bf16)tile[tx][ty + i * 8];
}

// Fused transpose of W1 [1024][4096] and W2 [4096][1024] (z picks).
__global__ __launch_bounds__(256) void transpose_ffw(
    const float* __restrict__ W1, const float* __restrict__ W2,
    __bf16* __restrict__ W1T, __bf16* __restrict__ W2T)
{
    __shared__ float tile[32][33];
    const int z = blockIdx.z;
    const float* in; __bf16* out; int R, C, c0, r0;
    if (z == 0) { in = W1; out = W1T; R = DM; C = 4 * DM; c0 = blockIdx.x * 32; r0 = blockIdx.y * 32; }
    else        { in = W2; out = W2T; R = 4 * DM; C = DM; c0 = blockIdx.y * 32; r0 = blockIdx.x * 32; }
    const int tx = threadIdx.x, ty = threadIdx.y;
#pragma unroll
    for (int i = 0; i < 4; i++)
        tile[ty + i * 8][tx] = in[(size_t)(r0 + ty + i * 8) * C + c0 + tx];
    __syncthreads();
#pragma unroll
    for (int i = 0; i < 4; i++)
        out[(size_t)(c0 + ty + i * 8) * R + r0 + tx] = (__bf16)tile[tx][ty + i * 8];
}

// ---------------------------------------------------------------------------
// Fill null-K row (kv==2048) with null_k, and zero Vt pad columns [2048,2056)
// ---------------------------------------------------------------------------
__global__ __launch_bounds__(256) void fill_null(
    const float* __restrict__ null_k, __bf16* __restrict__ Kb,
    __bf16* __restrict__ Vt)
{
    const int i = blockIdx.x * 256 + threadIdx.x;
    if (i < BATCH * DM) {
        const int b = i >> 10, d = i & (DM - 1);
        Kb[((size_t)b * NKV1 + NKVS) * DM + d] = (__bf16)null_k[d];
    }
    if (i < BATCH * NH * DHD * 8) {  // 16384
        const int bhd = i >> 3, kvp = i & 7;
        Vt[(size_t)bhd * 2056 + 2048 + kvp] = (__bf16)0.0f;
    }
}

// ---------------------------------------------------------------------------
// 256x256-tile GEMM core: C = A @ Bt^T.  512 threads (8 waves, 2Mx4N),
// per-wave 128x64 output.  K pipelined as 32 subtiles of BK=32 in a 4-slot
// LDS ring (128 KiB), staged via global_load_lds with 3 subtiles in flight
// (counted vmcnt(12), epilogue drain 8/4/0), raw s_barrier (no vmcnt drain).
// LDS source pre-swizzled: phys 16B chunk j of row r holds logical chunk
// j^(r&3); reads XOR the same -> 8-way bank conflict reduced to 4-way.
// Per-block K is fixed at 1024 (32 subtiles) for every use in this net.
// ---------------------------------------------------------------------------
__device__ __forceinline__ void g256_loop(
    const __bf16* __restrict__ A, const __bf16* __restrict__ Bt,
    int Kst, int kbeg, int m0, int n0,
    __bf16* sa, __bf16* sb, floatx4 (&acc)[8][4])
{
    const int tid = threadIdx.x, lane = tid & 63;
    const int g = lane >> 4, c = lane & 15;
    const int wave = tid >> 6;
    const int wm = wave >> 2, wn = wave & 3;

    // staging geometry: thread tid covers 16B chunk j of row r (rows 0..127
    // per issue; second issue adds 128 rows).  LDS dest is linear (tid*16B).
    const int r = tid >> 2, j = tid & 3;
    const int jx = (j ^ (r & 3)) * 8;            // swizzled source chunk (elems)
    const __bf16* Ag = A  + (size_t)(m0 + r) * Kst + kbeg + jx;
    const __bf16* Bg = Bt + (size_t)(n0 + r) * Kst + kbeg + jx;
    __bf16* la = sa + tid * 8;                   // byte offset tid*16
    __bf16* lb = sb + tid * 8;

#define G256_STAGE(ss, koff) do {                                          \
    gld_lds16(Ag + (koff),                      la + (ss) * 8192);         \
    gld_lds16(Ag + (size_t)128 * Kst + (koff),  la + (ss) * 8192 + 4096);  \
    gld_lds16(Bg + (koff),                      lb + (ss) * 8192);         \
    gld_lds16(Bg + (size_t)128 * Kst + (koff),  lb + (ss) * 8192 + 4096);  \
} while (0)

    // prologue: 3 subtiles in flight
    G256_STAGE(0, 0);
    G256_STAGE(1, 32);
    G256_STAGE(2, 64);

    const int ca = (c & 3) * 8;                  // read-side XOR (elems)
    const __bf16* ra = sa + (wm * 128 + c) * 32; // row base for A frags
    const __bf16* rb = sb + (wn * 64 + c) * 32;  // row base for B frags

    for (int s = 0; s < 32; s++) {
        if (s < 29) {
            G256_STAGE((s + 3) & 3, (s + 3) * 32);
            asm volatile("s_waitcnt vmcnt(12)" ::: "memory");
        } else if (s == 29) {
            asm volatile("s_waitcnt vmcnt(8)" ::: "memory");
        } else if (s == 30) {
            asm volatile("s_waitcnt vmcnt(4)" ::: "memory");
        } else {
            asm volatile("s_waitcnt vmcnt(0)" ::: "memory");
        }
        __builtin_amdgcn_sched_barrier(0);
        __builtin_amdgcn_s_barrier();            // all waves' subtile-s loads landed
        asm volatile("" ::: "memory");

        const int ss = (s & 3) * 8192;
        bf16x8 af[8], bfr[4];
#pragma unroll
        for (int i = 0; i < 8; i++)
            af[i] = *(const bf16x8*)(ra + ss + i * 512 + ((g * 8) ^ ca));
#pragma unroll
        for (int jj = 0; jj < 4; jj++)
            bfr[jj] = *(const bf16x8*)(rb + ss + jj * 512 + ((g * 8) ^ ca));

        __builtin_amdgcn_s_setprio(1);
#pragma unroll
        for (int i = 0; i < 8; i++)
#pragma unroll
            for (int jj = 0; jj < 4; jj++)
                acc[i][jj] = __builtin_amdgcn_mfma_f32_16x16x32_bf16(
                    af[i], bfr[jj], acc[i][jj], 0, 0, 0);
        __builtin_amdgcn_s_setprio(0);
        __builtin_amdgcn_sched_barrier(0);
        __builtin_amdgcn_s_barrier();            // reads of slot s done -> reusable
        asm volatile("" ::: "memory");
    }
#undef G256_STAGE
}

// XCD-bijective block swizzle: ntot = NX*NY blocks (ntot % 8 == 0); each XCD
// gets a contiguous chunk of logical tiles (2 M-rows x all N) for L2 reuse.
template<int NX>
__device__ __forceinline__ void g256_decode(int bid, int ntot, int& m0, int& n0)
{
    const int cpx = ntot >> 3;
    const int l = (bid & 7) * cpx + (bid >> 3);
    m0 = (l / NX) * 256;
    n0 = (l % NX) * 256;
}

// MODE 0: bf16 flat [M][N] (+bias, optional GELU).  MODE 4: split-K f32
// partials at [z][M][N] (blockIdx.z = K-slice of 1024).
template<int MODE, int ACT, int NX>
__global__ __launch_bounds__(512, 2) void g256(
    const __bf16* __restrict__ A, const __bf16* __restrict__ Bt,
    const float* __restrict__ bias, void* __restrict__ outp,
    int M, int N, int Kst)
{
    __shared__ __bf16 SA[4][256][32];
    __shared__ __bf16 SB[4][256][32];
    int m0, n0;
    g256_decode<NX>(blockIdx.x, NX * (M >> 8), m0, n0);
    const int kbeg = (MODE == 4) ? (blockIdx.z << 10) : 0;

    floatx4 acc[8][4] = {};
    g256_loop(A, Bt, Kst, kbeg, m0, n0, &SA[0][0][0], &SB[0][0][0], acc);

    const int tid = threadIdx.x, lane = tid & 63, wave = tid >> 6;
    const int g = lane >> 4, c = lane & 15;
    const int wm = wave >> 2, wn = wave & 3;

    __bf16* obf = (__bf16*)outp;
    float*  of  = (float*)outp;
#pragma unroll
    for (int i = 0; i < 8; i++) {
#pragma unroll
        for (int jj = 0; jj < 4; jj++) {
            const int row = m0 + wm * 128 + i * 16 + g * 4;
            const int col = n0 + wn * 64 + jj * 16 + c;
            const float bb = (MODE == 4) ? 0.0f : bias[col];
            float xs[4];
#pragma unroll
            for (int rr = 0; rr < 4; rr++) {
                float x = acc[i][jj][rr] + bb;
                if (ACT == 1) x = gelu_fast(x);
                xs[rr] = x;
            }
            if (MODE == 0) {
#pragma unroll
                for (int rr = 0; rr < 4; rr++)
                    obf[(size_t)(row + rr) * N + col] = (__bf16)xs[rr];
            } else if (MODE == 4) {
#pragma unroll
                for (int rr = 0; rr < 4; rr++)
                    of[((size_t)blockIdx.z * M + row + rr) * N + col] = xs[rr];
            }
        }
    }
}

// Fused Q/K/V projection on the 256-tile core.  grid (64,1,3).
__global__ __launch_bounds__(512, 2) void g256qkv(
    const __bf16* __restrict__ Xn, const __bf16* __restrict__ Yn,
    const __bf16* __restrict__ WqT, const __bf16* __restrict__ WkT,
    const __bf16* __restrict__ WvT,
    const float* __restrict__ bq, const float* __restrict__ bk,
    const float* __restrict__ bv,
    __bf16* __restrict__ Qbf, __bf16* __restrict__ Kbf,
    __bf16* __restrict__ Vt)
{
    __shared__ __bf16 SA[4][256][32];
    __shared__ __bf16 SB[4][256][32];
    const int z = blockIdx.z;
    const __bf16* A    = (z == 0) ? Xn  : Yn;
    const __bf16* Bt   = (z == 0) ? WqT : (z == 1) ? WkT : WvT;
    const float*  bias = (z == 0) ? bq  : (z == 1) ? bk  : bv;

    int m0, n0;
    g256_decode<4>(blockIdx.x, 64, m0, n0);

    floatx4 acc[8][4] = {};
    g256_loop(A, Bt, DM, 0, m0, n0, &SA[0][0][0], &SB[0][0][0], acc);

    const int tid = threadIdx.x, lane = tid & 63, wave = tid >> 6;
    const int g = lane >> 4, c = lane & 15;
    const int wm = wave >> 2, wn = wave & 3;

#pragma unroll
    for (int i = 0; i < 8; i++) {
#pragma unroll
        for (int jj = 0; jj < 4; jj++) {
            const int row = m0 + wm * 128 + i * 16 + g * 4;
            const int col = n0 + wn * 64 + jj * 16 + c;
            const float bb = bias[col];
            float xs[4];
#pragma unroll
            for (int rr = 0; rr < 4; rr++) xs[rr] = acc[i][jj][rr] + bb;
            if (z == 0) {
#pragma unroll
                for (int rr = 0; rr < 4; rr++)
                    Qbf[(size_t)(row + rr) * DM + col] = (__bf16)xs[rr];
            } else if (z == 1) {
#pragma unroll
                for (int rr = 0; rr < 4; rr++) {
                    const int r2 = row + rr;
                    Kbf[(size_t)(r2 + (r2 >> 11)) * DM + col] = (__bf16)xs[rr];
                }
            } else {
                const int b  = row >> 11;
                const int kv = row & 2047;
                const size_t base =
                    ((size_t)((b * NH + (col >> 6)) * DHD + (col & 63))) * 2056 + kv;
                bf16x4 pk;
                pk[0] = (__bf16)xs[0]; pk[1] = (__bf16)xs[1];
                pk[2] = (__bf16)xs[2]; pk[3] = (__bf16)xs[3];
                *(bf16x4*)(Vt + base) = pk;
            }
        }
    }
}

// ---------------------------------------------------------------------------
// FF2 split-K reduction: out = sum_z partials[z] + bias + Hres.  float4/thread.
// ---------------------------------------------------------------------------
__global__ __launch_bounds__(256) void ff2_reduce(
    const float* __restrict__ part, const float* __restrict__ bias,
    const float* __restrict__ Hres, float* __restrict__ out)
{
    const size_t f4 = (size_t)blockIdx.x * 256 + threadIdx.x;  // float4 index
    const int c4 = (int)(f4 & (DM / 4 - 1));
    const size_t stride4 = (size_t)ROWS * DM / 4;
    float4 a = ((const float4*)part)[f4];
    const float4 p1 = ((const float4*)part)[f4 + stride4];
    const float4 p2 = ((const float4*)part)[f4 + 2 * stride4];
    const float4 p3 = ((const float4*)part)[f4 + 3 * stride4];
    const float4 b  = ((const float4*)bias)[c4];
    const float4 hr = ((const float4*)Hres)[f4];
    a.x += p1.x + p2.x + p3.x + b.x + hr.x;
    a.y += p1.y + p2.y + p3.y + b.y + hr.y;
    a.z += p1.z + p2.z + p3.z + b.z + hr.z;
    a.w += p1.w + p2.w + p3.w + b.w + hr.w;
    ((float4*)out)[f4] = a;
}

// ---------------------------------------------------------------------------
// Flash attention (unchanged from round 2): 128 q/block, gld_lds staging with
// XOR-swizzled source, XCD-local heads, one barrier per KV tile.
// ---------------------------------------------------------------------------
__global__ __launch_bounds__(256, 2) void attn_kernel(
    const __bf16* __restrict__ Q, const __bf16* __restrict__ Kb,
    const __bf16* __restrict__ Vt, __bf16* __restrict__ O)
{
    __shared__ __bf16 Ks[2][64][64];   // [kv][d]   16 KB
    __shared__ __bf16 Vs[2][64][64];   // [d][kv]   16 KB

    const int tid = threadIdx.x, lane = tid & 63, w = tid >> 6;
    const int g = lane >> 4, c = lane & 15;

    const int hw   = blockIdx.x;
    const int slot = hw >> 3;
    const int hb   = (hw & 7) | ((slot >> 4) << 3);   // 0..31
    const int h = hb & 15, b = hb >> 4;
    const int q0w = (slot & 15) * 128 + w * 32;

    const float QSC = 0.03125f * 1.44269504088896f;
    bf16x8 qf[2][2];
#pragma unroll
    for (int qt = 0; qt < 2; qt++) {
        const __bf16* Qbase = Q + ((size_t)(b * NQS + q0w + qt * 16 + c)) * DM + h * DHD;
        qf[qt][0] = *(const bf16x8*)(Qbase + g * 8);
        qf[qt][1] = *(const bf16x8*)(Qbase + 32 + g * 8);
#pragma unroll
        for (int e = 0; e < 8; e++) {
            qf[qt][0][e] = (__bf16)((float)qf[qt][0][e] * QSC);
            qf[qt][1][e] = (__bf16)((float)qf[qt][1][e] * QSC);
        }
    }

    floatx4 lacc[2] = {};
    floatx4 oacc[2][4] = {};

    const int srow = tid >> 3;                    // LDS row 0..31 (and +32)
    const int schk = (tid & 7) ^ (srow & 7);      // swizzled 16B source chunk
    const __bf16* Kg  = Kb + (size_t)b * NKV1 * DM + h * DHD + schk * 8;
    const __bf16* Vg  = Vt + ((size_t)(b * NH + h) * DHD + srow) * 2056;
    const __bf16* Vg2 = Vg + (size_t)32 * 2056;
    const int vcol0 = schk * 8;

    auto stage = [&](int p, int kv0, bool tail) {
        __bf16* kd0 = &Ks[p][0][0]  + tid * 8;
        __bf16* kd1 = &Ks[p][32][0] + tid * 8;
        __bf16* vd0 = &Vs[p][0][0]  + tid * 8;
        __bf16* vd1 = &Vs[p][32][0] + tid * 8;
        if (!tail) {
            gld_lds16(Kg + (size_t)(kv0 + srow) * DM, kd0);
            gld_lds16(Kg + (size_t)(kv0 + srow + 32) * DM, kd1);
            gld_lds16(Vg + kv0 + vcol0, vd0);
            gld_lds16(Vg2 + kv0 + vcol0, vd1);
        } else {
            const int r0 = min(kv0 + srow, NKVS);
            const int r1 = min(kv0 + srow + 32, NKVS);
            const int vc = min(kv0 + vcol0, NKVS);
            gld_lds16(Kg + (size_t)r0 * DM, kd0);
            gld_lds16(Kg + (size_t)r1 * DM, kd1);
            gld_lds16(Vg + vc, vd0);
            gld_lds16(Vg2 + vc, vd1);
        }
    };

    auto compute = [&](int p, int kv0, bool tail) {
        floatx4 s[2][4];
#pragma unroll
        for (int qt = 0; qt < 2; qt++)
#pragma unroll
            for (int kvt = 0; kvt < 4; kvt++)
#pragma unroll
                for (int r = 0; r < 4; r++) s[qt][kvt][r] = -6.0f;

        const int sw = c & 7;
        __builtin_amdgcn_s_setprio(1);
#pragma unroll
        for (int kvt = 0; kvt < 4; kvt++) {
            const bf16x8 kf0 = *(const bf16x8*)&Ks[p][kvt * 16 + c][(g ^ sw) * 8];
            const bf16x8 kf1 = *(const bf16x8*)&Ks[p][kvt * 16 + c][((4 | g) ^ sw) * 8];
#pragma unroll
            for (int qt = 0; qt < 2; qt++) {
                s[qt][kvt] = __builtin_amdgcn_mfma_f32_16x16x32_bf16(kf0, qf[qt][0], s[qt][kvt], 0, 0, 0);
                s[qt][kvt] = __builtin_amdgcn_mfma_f32_16x16x32_bf16(kf1, qf[qt][1], s[qt][kvt], 0, 0, 0);
            }
        }
        __builtin_amdgcn_s_setprio(0);

        if (tail) {
#pragma unroll
            for (int qt = 0; qt < 2; qt++)
#pragma unroll
                for (int kvt = 0; kvt < 4; kvt++)
#pragma unroll
                    for (int r = 0; r < 4; r++)
                        if (kv0 + kvt * 16 + g * 4 + r >= NKV1) s[qt][kvt][r] = -1e30f;
        }

        shortx4 pf[2][4];
#pragma unroll
        for (int qt = 0; qt < 2; qt++)
#pragma unroll
            for (int kvt = 0; kvt < 4; kvt++) {
                float p0 = __builtin_amdgcn_exp2f(s[qt][kvt][0]);
                float p1 = __builtin_amdgcn_exp2f(s[qt][kvt][1]);
                float p2 = __builtin_amdgcn_exp2f(s[qt][kvt][2]);
                float p3 = __builtin_amdgcn_exp2f(s[qt][kvt][3]);
                lacc[qt][0] += p0; lacc[qt][1] += p1;
                lacc[qt][2] += p2; lacc[qt][3] += p3;
                uint32x2 pk;
                pk[0] = (__builtin_bit_cast(unsigned int, p0) >> 16) |
                        (__builtin_bit_cast(unsigned int, p1) & 0xFFFF0000u);
                pk[1] = (__builtin_bit_cast(unsigned int, p2) >> 16) |
                        (__builtin_bit_cast(unsigned int, p3) & 0xFFFF0000u);
                pf[qt][kvt] = __builtin_bit_cast(shortx4, pk);
            }

        __builtin_amdgcn_s_setprio(1);
#pragma unroll
        for (int kvt = 0; kvt < 4; kvt++) {
            shortx4 vfr[4];
#pragma unroll
            for (int dt = 0; dt < 4; dt++) {
                const int slotp = (kvt * 2 + (g >> 1)) ^ sw;
                vfr[dt] = *(const shortx4*)&Vs[p][dt * 16 + c][slotp * 8 + (g & 1) * 4];
            }
#pragma unroll
            for (int dt = 0; dt < 4; dt++)
#pragma unroll
                for (int qt = 0; qt < 2; qt++)
                    oacc[qt][dt] = __builtin_amdgcn_mfma_f32_16x16x16bf16_1k(
                        vfr[dt], pf[qt][kvt], oacc[qt][dt], 0, 0, 0);
        }
        __builtin_amdgcn_s_setprio(0);
    };

    stage(0, 0, false);
    __syncthreads();
    for (int it = 0; it < 32; it++) {
        stage((it + 1) & 1, (it + 1) * 64, it == 31);
        compute(it & 1, it * 64, false);
        __syncthreads();
    }
    compute(0, 2048, true);

#pragma unroll
    for (int qt = 0; qt < 2; qt++) {
        float l = lacc[qt][0] + lacc[qt][1] + lacc[qt][2] + lacc[qt][3];
        l += __shfl_xor(l, 16);
        l += __shfl_xor(l, 32);
        const float inv_l = 1.0f / l;
        __bf16* Ob = O + ((size_t)(b * NQS + q0w + qt * 16 + c)) * DM + h * DHD;
#pragma unroll
        for (int dt = 0; dt < 4; dt++) {
            bf16x4 ob;
#pragma unroll
            for (int r = 0; r < 4; r++) ob[r] = (__bf16)(oacc[qt][dt][r] * inv_l);
            *(bf16x4*)(Ob + dt * 16 + g * 4) = ob;
        }
    }
}

// ---------------------------------------------------------------------------
extern "C" void kernel_launch(void* const* d_in, const int* in_sizes, int n_in,
                              void* d_out, int out_size, void* d_ws, size_t ws_size,
                              hipStream_t stream)
{
    const float* X      = (const float*)d_in[0];
    const float* Y      = (const float*)d_in[1];
    const float* Wq     = (const float*)d_in[2];
    const float* bq     = (const float*)d_in[3];
    const float* Wk     = (const float*)d_in[4];
    const float* bk     = (const float*)d_in[5];
    const float* Wv     = (const float*)d_in[6];
    const float* bv     = (const float*)d_in[7];
    const float* null_k = (const float*)d_in[8];
    const float* g0     = (const float*)d_in[9];
    const float* b0     = (const float*)d_in[10];
    const float* g0kv   = (const float*)d_in[11];
    const float* b0kv   = (const float*)d_in[12];
    const float* g1     = (const float*)d_in[13];
    const float* b1     = (const float*)d_in[14];
    const float* W1     = (const float*)d_in[15];
    const float* bf1    = (const float*)d_in[16];
    const float* W2     = (const float*)d_in[17];
    const float* bf2    = (const float*)d_in[18];
    float* out = (float*)d_out;

    // workspace carve (bytes).
    char* p = (char*)d_ws;
    __bf16* W2T  = (__bf16*)p; p += (size_t)4 * DM * DM * 2;          // [1024][4096]
    float*  Hres = (float*)p;  p += (size_t)ROWS * DM * 4;
    __bf16* Gbf  = (__bf16*)p; p += (size_t)ROWS * 4 * DM * 2;
    char* scratch = p;                                                // dead by FF2
    __bf16* Xn   = (__bf16*)p; p += (size_t)ROWS * DM * 2;
    __bf16* Yn   = (__bf16*)p; p += (size_t)ROWS * DM * 2;
    __bf16* WqT  = (__bf16*)p; p += (size_t)DM * DM * 2;
    __bf16* WkT  = (__bf16*)p; p += (size_t)DM * DM * 2;
    __bf16* WvT  = (__bf16*)p; p += (size_t)DM * DM * 2;
    __bf16* W1T  = (__bf16*)p; p += (size_t)4 * DM * DM * 2;          // [4096][1024]
    __bf16* Qbf  = (__bf16*)p; p += (size_t)ROWS * DM * 2;
    __bf16* Kbf  = (__bf16*)p; p += (size_t)BATCH * NKV1 * DM * 2;
    __bf16* Vt   = (__bf16*)p; p += (size_t)BATCH * NH * DHD * 2056 * 2;
    __bf16* Obf  = (__bf16*)p; p += (size_t)ROWS * DM * 2;
    __bf16* Hr   = (__bf16*)p; p += (size_t)ROWS * DM * 2;
    float* Part  = (float*)scratch;  // FF2 partials: 4 x ROWS x DM f32 = 67 MB

    // 1. LayerNorms (fused X+Y, one launch)
    ln2_to_bf16<<<2 * ROWS, 256, 0, stream>>>(X, Y, g0, b0, g0kv, b0kv, Xn, Yn);

    // 2. weight transposes (f32 -> bf16, W^T), two launches total
    transpose3_f32_bf16<<<dim3(DM / 32, DM / 32, 3), dim3(32, 8), 0, stream>>>(
        Wq, Wk, Wv, WqT, WkT, WvT);
    transpose_ffw<<<dim3(128, 32, 2), dim3(32, 8), 0, stream>>>(W1, W2, W1T, W2T);

    // 3. fused Q/K/V projections on the 256-tile pipelined core
    g256qkv<<<dim3(64, 1, 3), 512, 0, stream>>>(
        Xn, Yn, WqT, WkT, WvT, bq, bk, bv, Qbf, Kbf, Vt);
    fill_null<<<64, 256, 0, stream>>>(null_k, Kbf, Vt);

    // 4. attention (128 q/block, gld_lds staging, XCD-local heads)
    attn_kernel<<<dim3(512), 256, 0, stream>>>(Qbf, Kbf, Vt, Obf);

    // 5. residual + LN
    resid_ln<<<ROWS, 256, 0, stream>>>(X, Obf, g1, b1, Hres, Hr);

    // 6. FFN on the 256-tile pipelined core
    g256<0, 1, 16><<<dim3(256), 512, 0, stream>>>(
        Hr, W1T, bf1, (void*)Gbf, ROWS, 4 * DM, DM);
    g256<4, 0, 4><<<dim3(64, 1, 4), 512, 0, stream>>>(
        Gbf, W2T, bf2, (void*)Part, ROWS, DM, 4 * DM);
    ff2_reduce<<<ROWS * DM / 1024, 256, 0, stream>>>(Part, bf2, Hres, out);
}